// Round 1
// baseline (1655.059 us; speedup 1.0000x reference)
//
#include <hip/hip_runtime.h>
#include <math.h>

#define N_NODES_ 100000
#define N_EDGES_ 400000
#define NPB 8
#define THREADS 512

// rep index -> offset (r*9+c) inside an 81-float 9x9 block
__constant__ int REP_OFF_C[45] = {
  0,                               // s
  10, 20, 30,                      // p diag
  11, 12, 21,                      // p upper
  40, 50, 60, 70, 80,              // d diag
  41, 42, 43, 44, 51, 52, 53, 61, 62, 71,  // d upper
  1, 2, 3,                         // sp
  4, 5, 6, 7, 8,                   // sd
  13, 14, 15, 16, 17, 22, 23, 24, 25, 26, 31, 32, 33, 34, 35  // pd
};

__global__ void zero_u32_k(unsigned* p, int n) {
  int i = blockIdx.x * blockDim.x + threadIdx.x;
  if (i < n) p[i] = 0u;
}

__global__ void hist_k(const int* __restrict__ row, unsigned* __restrict__ deg, int n) {
  int i = blockIdx.x * blockDim.x + threadIdx.x;
  if (i < n) atomicAdd(&deg[row[i]], 1u);
}

// single-block exclusive scan of deg[0..n) -> row_ptr[0..n], also writes cursor copy
__global__ __launch_bounds__(1024)
void scan_k(const unsigned* __restrict__ deg, unsigned* __restrict__ row_ptr,
            unsigned* __restrict__ cursor, unsigned n) {
  __shared__ unsigned wsum[16];
  __shared__ unsigned carry_s;
  const int tid = threadIdx.x;
  const int lane = tid & 63;
  const int w = tid >> 6;
  if (tid == 0) carry_s = 0u;
  __syncthreads();
  const unsigned CH = 1024u * 8u;
  for (unsigned base = 0; base < n; base += CH) {
    unsigned v[8]; unsigned s = 0;
    #pragma unroll
    for (int q = 0; q < 8; ++q) {
      unsigned i = base + (unsigned)tid * 8u + q;
      v[q] = (i < n) ? deg[i] : 0u;
      s += v[q];
    }
    unsigned incl = s;
    #pragma unroll
    for (int off = 1; off < 64; off <<= 1) {
      unsigned t2 = __shfl_up(incl, off);
      if (lane >= off) incl += t2;
    }
    if (lane == 63) wsum[w] = incl;
    __syncthreads();
    if (tid == 0) {
      unsigned a = 0;
      #pragma unroll
      for (int i2 = 0; i2 < 16; ++i2) { unsigned t3 = wsum[i2]; wsum[i2] = a; a += t3; }
    }
    __syncthreads();
    unsigned run = carry_s + wsum[w] + (incl - s);
    #pragma unroll
    for (int q = 0; q < 8; ++q) {
      unsigned i = base + (unsigned)tid * 8u + q;
      if (i < n) { row_ptr[i] = run; cursor[i] = run; }
      run += v[q];
    }
    __syncthreads();
    if (tid == 1023) carry_s = run;  // = carry + chunk total
    __syncthreads();
  }
  if (tid == 0) row_ptr[n] = carry_s;
}

__global__ void scatter_k(const int* __restrict__ row, unsigned* __restrict__ cursor,
                          unsigned* __restrict__ edge_list, int n) {
  int i = blockIdx.x * blockDim.x + threadIdx.x;
  if (i < n) {
    unsigned p = atomicAdd(&cursor[row[i]], 1u);
    edge_list[p] = (unsigned)i;
  }
}

// Wc[k][r] = sum_h W_fc1[k,h]*W_fc2[h,r] * 1/(45*sqrt(32)*sqrt(64))
__global__ void wc_k(const float* __restrict__ fc1, const float* __restrict__ fc2,
                     float* __restrict__ Wc) {
  int idx = blockIdx.x * blockDim.x + threadIdx.x;
  if (idx < 32 * 45) {
    int k = idx / 45, r = idx - k * 45;
    float s = 0.f;
    #pragma unroll
    for (int h = 0; h < 64; ++h) s += fc1[k * 64 + h] * fc2[h * 45 + r];
    const float SCALE = 1.0f / (45.0f * 8.0f * sqrtf(32.0f));
    Wc[idx] = s * SCALE;
  }
}

// Fused: per block of 8 nodes, compute A[nc][j][k] = sum_i fn[nc][i]*W_tp[i][j][k]
// in LDS, then for each incident (edge,channel): tp[k] = sum_j fe_rep[j]*A[nc][j][k],
// out[r] = sum_k tp[k]*Wc[k][r].
__global__ __launch_bounds__(THREADS)
void fused_k(const float* __restrict__ f_nodes, const float* __restrict__ f_edges,
             const float* __restrict__ W_tp, const float* __restrict__ Wc,
             const unsigned* __restrict__ row_ptr, const unsigned* __restrict__ edge_list,
             float* __restrict__ out) {
  __shared__ float A_lds[16 * 1440];        // [nc][j*32+k], 92160 B
  __shared__ float fn_lds[45][16];          // [i][nc]
  __shared__ float ferep_lds[8][2][48];     // [wave][taskhalf][j]
  __shared__ float tp_lds[8][2][32];
  __shared__ unsigned tasks[512];
  __shared__ int t_count;

  const int tid = threadIdx.x;
  const int node_base = blockIdx.x * NPB;

  if (tid == 0) t_count = 0;
  for (int idx = tid; idx < NPB * 2 * 45; idx += THREADS) {
    int ln = idx / 90; int rem = idx - ln * 90; int c = rem / 45; int j = rem - c * 45;
    int node = node_base + ln;
    fn_lds[j][ln * 2 + c] = f_nodes[(size_t)node * 162 + c * 81 + REP_OFF_C[j]];
  }
  __syncthreads();

  // build task list (threads 0..7), overlapped with phase A by the other threads
  if (tid < NPB) {
    int n = node_base + tid;
    unsigned s = row_ptr[n], e = row_ptr[n + 1];
    for (unsigned q = s; q < e; ++q) {
      unsigned eid = edge_list[q];
      int pos = atomicAdd(&t_count, 2);
      if (pos + 1 < 512) {
        unsigned b = (eid << 4) | ((unsigned)tid << 1);
        tasks[pos] = b;
        tasks[pos + 1] = b | 1u;
      }
    }
  }

  // ---- phase A: A[nc][jk] over jk = tid, tid+512, tid+1024 ----
  float acc0[16], acc1[16], acc2[16];
  #pragma unroll
  for (int nc = 0; nc < 16; ++nc) { acc0[nc] = 0.f; acc1[nc] = 0.f; acc2[nc] = 0.f; }
  const int jk0 = tid, jk1 = tid + THREADS, jk2 = tid + 2 * THREADS;
  const bool v2 = (jk2 < 1440);
  for (int i = 0; i < 45; ++i) {
    float fv[16];
    #pragma unroll
    for (int q = 0; q < 4; ++q)
      *(float4*)&fv[q * 4] = *(const float4*)&fn_lds[i][q * 4];
    const float* wrow = W_tp + i * 1440;
    float w0 = wrow[jk0];
    float w1 = wrow[jk1];
    float w2 = v2 ? wrow[jk2] : 0.f;
    #pragma unroll
    for (int nc = 0; nc < 16; ++nc) {
      acc0[nc] = fmaf(w0, fv[nc], acc0[nc]);
      acc1[nc] = fmaf(w1, fv[nc], acc1[nc]);
      acc2[nc] = fmaf(w2, fv[nc], acc2[nc]);
    }
  }
  #pragma unroll
  for (int nc = 0; nc < 16; ++nc) {
    A_lds[nc * 1440 + jk0] = acc0[nc];
    A_lds[nc * 1440 + jk1] = acc1[nc];
    if (v2) A_lds[nc * 1440 + jk2] = acc2[nc];
  }
  __syncthreads();

  // ---- phase B: edges ----
  const int wid = tid >> 6, lane = tid & 63;
  const int th = lane >> 5, k = lane & 31;
  // preload this lane's two Wc columns into registers (r = k and r = k+32)
  float wc1[32], wc2[32];
  #pragma unroll
  for (int k2 = 0; k2 < 32; ++k2) {
    wc1[k2] = Wc[k2 * 45 + k];
    wc2[k2] = (k < 13) ? Wc[k2 * 45 + k + 32] : 0.f;
  }
  const int T = t_count;
  for (int p2 = wid * 2; p2 < T; p2 += 16) {
    const int idx = p2 + th;
    const bool valid = idx < T;
    const unsigned task = tasks[valid ? idx : 0];
    const int e = (int)(task >> 4);
    const int nc = (int)(task & 15u);   // ln*2 + c
    const int c = (int)(task & 1u);
    const float* fe = f_edges + (size_t)e * 162 + c * 81;
    ferep_lds[wid][th][k] = fe[REP_OFF_C[k]];
    if (k < 13) ferep_lds[wid][th][k + 32] = fe[REP_OFF_C[k + 32]];
    asm volatile("s_waitcnt lgkmcnt(0)" ::: "memory");
    float acc = 0.f;
    const float* Arow = &A_lds[nc * 1440 + k];
    const float* fr = &ferep_lds[wid][th][0];
    #pragma unroll
    for (int j = 0; j < 45; ++j)
      acc = fmaf(fr[j], Arow[j * 32], acc);
    tp_lds[wid][th][k] = acc;
    asm volatile("s_waitcnt lgkmcnt(0)" ::: "memory");
    const float* tpp = &tp_lds[wid][th][0];
    float o1 = 0.f, o2 = 0.f;
    #pragma unroll
    for (int k2 = 0; k2 < 32; ++k2) {
      float tv = tpp[k2];
      o1 = fmaf(tv, wc1[k2], o1);
      o2 = fmaf(tv, wc2[k2], o2);
    }
    if (valid) {
      float* op = out + (size_t)e * 90 + c * 45;
      op[k] = o1;
      if (k < 13) op[k + 32] = o2;
    }
  }
}

extern "C" void kernel_launch(void* const* d_in, const int* in_sizes, int n_in,
                              void* d_out, int out_size, void* d_ws, size_t ws_size,
                              hipStream_t stream) {
  const float* f_nodes = (const float*)d_in[0];
  const float* f_edges = (const float*)d_in[1];
  const int* edge_index = (const int*)d_in[2];   // row = first N_EDGES ints
  const float* W_tp = (const float*)d_in[3];
  const float* W_fc1 = (const float*)d_in[4];
  const float* W_fc2 = (const float*)d_in[5];
  float* out = (float*)d_out;

  // workspace layout (needs ~2.41 MB)
  char* ws = (char*)d_ws;
  unsigned* deg_cursor = (unsigned*)ws;                       // 100000 u32
  unsigned* row_ptr   = (unsigned*)(ws + 400000);             // 100001 u32
  unsigned* edge_list = (unsigned*)(ws + 800016);             // 400000 u32
  float*    Wc        = (float*)(ws + 800016 + 1600000);      // 1440 f32

  const int* row = edge_index;

  zero_u32_k<<<(N_NODES_ + 255) / 256, 256, 0, stream>>>(deg_cursor, N_NODES_);
  wc_k<<<6, 256, 0, stream>>>(W_fc1, W_fc2, Wc);
  hist_k<<<(N_EDGES_ + 255) / 256, 256, 0, stream>>>(row, deg_cursor, N_EDGES_);
  scan_k<<<1, 1024, 0, stream>>>(deg_cursor, row_ptr, deg_cursor, N_NODES_);
  scatter_k<<<(N_EDGES_ + 255) / 256, 256, 0, stream>>>(row, deg_cursor, edge_list, N_EDGES_);
  fused_k<<<N_NODES_ / NPB, THREADS, 0, stream>>>(f_nodes, f_edges, W_tp, Wc,
                                                  row_ptr, edge_list, out);
}

// Round 2
// 1564.152 us; speedup vs baseline: 1.0581x; 1.0581x over previous
//
#include <hip/hip_runtime.h>
#include <math.h>

#define N_NODES_ 100000
#define N_EDGES_ 400000
#define NPB 4
#define THREADS 256

// rep index -> offset (r*9+c) inside an 81-float 9x9 block
// constexpr copy: folded to immediate offsets in fully-unrolled loops
constexpr int REP_OFF[45] = {
  0,
  10, 20, 30,
  11, 12, 21,
  40, 50, 60, 70, 80,
  41, 42, 43, 44, 51, 52, 53, 61, 62, 71,
  1, 2, 3,
  4, 5, 6, 7, 8,
  13, 14, 15, 16, 17, 22, 23, 24, 25, 26, 31, 32, 33, 34, 35
};
// runtime-indexed copy for the staging loop
__constant__ int REP_OFF_C[45] = {
  0,
  10, 20, 30,
  11, 12, 21,
  40, 50, 60, 70, 80,
  41, 42, 43, 44, 51, 52, 53, 61, 62, 71,
  1, 2, 3,
  4, 5, 6, 7, 8,
  13, 14, 15, 16, 17, 22, 23, 24, 25, 26, 31, 32, 33, 34, 35
};

__global__ void hist_k(const int* __restrict__ row, unsigned* __restrict__ deg, int n) {
  int i = blockIdx.x * blockDim.x + threadIdx.x;
  if (i < n) atomicAdd(&deg[row[i]], 1u);
}

// single-block exclusive scan of deg[0..n) -> row_ptr[0..n], also writes cursor copy
__global__ __launch_bounds__(1024)
void scan_k(const unsigned* __restrict__ deg, unsigned* __restrict__ row_ptr,
            unsigned* __restrict__ cursor, unsigned n) {
  __shared__ unsigned wsum[16];
  __shared__ unsigned carry_s;
  const int tid = threadIdx.x;
  const int lane = tid & 63;
  const int w = tid >> 6;
  if (tid == 0) carry_s = 0u;
  __syncthreads();
  const unsigned CH = 1024u * 8u;
  for (unsigned base = 0; base < n; base += CH) {
    unsigned v[8]; unsigned s = 0;
    #pragma unroll
    for (int q = 0; q < 8; ++q) {
      unsigned i = base + (unsigned)tid * 8u + q;
      v[q] = (i < n) ? deg[i] : 0u;
      s += v[q];
    }
    unsigned incl = s;
    #pragma unroll
    for (int off = 1; off < 64; off <<= 1) {
      unsigned t2 = __shfl_up(incl, off);
      if (lane >= off) incl += t2;
    }
    if (lane == 63) wsum[w] = incl;
    __syncthreads();
    if (tid == 0) {
      unsigned a = 0;
      #pragma unroll
      for (int i2 = 0; i2 < 16; ++i2) { unsigned t3 = wsum[i2]; wsum[i2] = a; a += t3; }
    }
    __syncthreads();
    unsigned run = carry_s + wsum[w] + (incl - s);
    #pragma unroll
    for (int q = 0; q < 8; ++q) {
      unsigned i = base + (unsigned)tid * 8u + q;
      if (i < n) { row_ptr[i] = run; cursor[i] = run; }
      run += v[q];
    }
    __syncthreads();
    if (tid == 1023) carry_s = run;
    __syncthreads();
  }
  if (tid == 0) row_ptr[n] = carry_s;
}

__global__ void scatter_k(const int* __restrict__ row, unsigned* __restrict__ cursor,
                          unsigned* __restrict__ edge_list, int n) {
  int i = blockIdx.x * blockDim.x + threadIdx.x;
  if (i < n) {
    unsigned p = atomicAdd(&cursor[row[i]], 1u);
    edge_list[p] = (unsigned)i;
  }
}

// Wc[k][r] = sum_h W_fc1[k,h]*W_fc2[h,r] * 1/(45*sqrt(32)*sqrt(64))
__global__ void wc_k(const float* __restrict__ fc1, const float* __restrict__ fc2,
                     float* __restrict__ Wc) {
  int idx = blockIdx.x * blockDim.x + threadIdx.x;
  if (idx < 32 * 45) {
    int k = idx / 45, r = idx - k * 45;
    float s = 0.f;
    #pragma unroll
    for (int h = 0; h < 64; ++h) s += fc1[k * 64 + h] * fc2[h * 45 + r];
    const float SCALE = 1.0f / (45.0f * 8.0f * sqrtf(32.0f));
    Wc[idx] = s * SCALE;
  }
}

// Per block: 4 nodes (8 node-channels).
// Phase A (all 256 threads): A[nc][j][k] = sum_i fn[nc][i]*W_tp[i][j][k] -> LDS (46 KB).
// Phase B: wave w owns node w. Lane (th,k): A-column cached in 45 VGPRs.
// Per edge: fe rep values via uniform global loads (imm offsets), tp via 45 FMA,
// cross-lane tp exchange via b128 LDS broadcasts, out = tp . Wc with Wc in regs.
__global__ __launch_bounds__(THREADS, 3)
void fused_k(const float* __restrict__ f_nodes, const float* __restrict__ f_edges,
             const float* __restrict__ W_tp, const float* __restrict__ Wc,
             const unsigned* __restrict__ row_ptr, const unsigned* __restrict__ edge_list,
             float* __restrict__ out) {
  __shared__ float A_lds[8 * 1440];   // [nc][j*32+k]  46080 B
  __shared__ float fn_lds[45][8];     // [i][nc]
  __shared__ float tp_lds[4][64];     // [wave][th*32+k]

  const int tid = threadIdx.x;
  const int node_base = blockIdx.x * NPB;

  // stage fn reps
  for (int idx = tid; idx < NPB * 2 * 45; idx += THREADS) {
    int ncl = idx / 45; int j = idx - ncl * 45;
    int ln = ncl >> 1, c = ncl & 1;
    fn_lds[j][ncl] = f_nodes[(size_t)(node_base + ln) * 162 + c * 81 + REP_OFF_C[j]];
  }
  __syncthreads();

  // ---- phase A ----
  float accA[8][6];
  #pragma unroll
  for (int nc = 0; nc < 8; ++nc)
    #pragma unroll
    for (int q = 0; q < 6; ++q) accA[nc][q] = 0.f;

  for (int i = 0; i < 45; ++i) {
    float fv[8];
    *(float4*)&fv[0] = *(const float4*)&fn_lds[i][0];
    *(float4*)&fv[4] = *(const float4*)&fn_lds[i][4];
    const float* wrow = W_tp + i * 1440;
    #pragma unroll
    for (int q = 0; q < 6; ++q) {
      const int jk = tid + q * THREADS;
      float w = (jk < 1440) ? wrow[jk] : 0.f;
      #pragma unroll
      for (int nc = 0; nc < 8; ++nc)
        accA[nc][q] = fmaf(w, fv[nc], accA[nc][q]);
    }
  }
  #pragma unroll
  for (int q = 0; q < 6; ++q) {
    const int jk = tid + q * THREADS;
    if (jk < 1440) {
      #pragma unroll
      for (int nc = 0; nc < 8; ++nc) A_lds[nc * 1440 + jk] = accA[nc][q];
    }
  }
  __syncthreads();

  // ---- phase B ----
  const int wv = tid >> 6, lane = tid & 63;
  const int th = lane >> 5, k = lane & 31;

  // Wc columns for this lane's output r (= lane), r<45
  float wcr[32];
  {
    const int r = (lane < 45) ? lane : 0;
    #pragma unroll
    for (int k2 = 0; k2 < 32; ++k2) wcr[k2] = Wc[k2 * 45 + r];
  }

  // cache A column: Areg[j] = A[wv*2+th][j][k]
  float Areg[45];
  {
    const float* Ab = &A_lds[(wv * 2 + th) * 1440 + k];
    #pragma unroll
    for (int j = 0; j < 45; ++j) Areg[j] = Ab[j * 32];
  }

  const int n = node_base + wv;
  const unsigned s = row_ptr[n], e = row_ptr[n + 1];
  for (unsigned q = s; q < e; ++q) {
    const unsigned eid = edge_list[q];
    const float* fe = f_edges + (size_t)eid * 162 + th * 81;
    float acc = 0.f;
    #pragma unroll
    for (int j = 0; j < 45; ++j)
      acc = fmaf(fe[REP_OFF[j]], Areg[j], acc);
    tp_lds[wv][lane] = acc;
    asm volatile("s_waitcnt lgkmcnt(0)" ::: "memory");
    #pragma unroll
    for (int c = 0; c < 2; ++c) {
      const float* tb = &tp_lds[wv][c * 32];
      float o = 0.f;
      #pragma unroll
      for (int q2 = 0; q2 < 8; ++q2) {
        float4 t4 = *(const float4*)&tb[q2 * 4];
        o = fmaf(t4.x, wcr[q2 * 4 + 0], o);
        o = fmaf(t4.y, wcr[q2 * 4 + 1], o);
        o = fmaf(t4.z, wcr[q2 * 4 + 2], o);
        o = fmaf(t4.w, wcr[q2 * 4 + 3], o);
      }
      if (lane < 45) out[(size_t)eid * 90 + c * 45 + lane] = o;
    }
  }
}

extern "C" void kernel_launch(void* const* d_in, const int* in_sizes, int n_in,
                              void* d_out, int out_size, void* d_ws, size_t ws_size,
                              hipStream_t stream) {
  const float* f_nodes = (const float*)d_in[0];
  const float* f_edges = (const float*)d_in[1];
  const int* edge_index = (const int*)d_in[2];   // row = first N_EDGES ints
  const float* W_tp = (const float*)d_in[3];
  const float* W_fc1 = (const float*)d_in[4];
  const float* W_fc2 = (const float*)d_in[5];
  float* out = (float*)d_out;

  char* ws = (char*)d_ws;
  unsigned* deg_cursor = (unsigned*)ws;                       // 100000 u32
  unsigned* row_ptr   = (unsigned*)(ws + 400000);             // 100001 u32
  unsigned* edge_list = (unsigned*)(ws + 800016);             // 400000 u32
  float*    Wc        = (float*)(ws + 800016 + 1600000);      // 1440 f32

  const int* row = edge_index;

  hipMemsetAsync(deg_cursor, 0, (size_t)N_NODES_ * 4, stream);
  wc_k<<<6, 256, 0, stream>>>(W_fc1, W_fc2, Wc);
  hist_k<<<(N_EDGES_ + 255) / 256, 256, 0, stream>>>(row, deg_cursor, N_EDGES_);
  scan_k<<<1, 1024, 0, stream>>>(deg_cursor, row_ptr, deg_cursor, N_NODES_);
  scatter_k<<<(N_EDGES_ + 255) / 256, 256, 0, stream>>>(row, deg_cursor, edge_list, N_EDGES_);
  fused_k<<<N_NODES_ / NPB, THREADS, 0, stream>>>(f_nodes, f_edges, W_tp, Wc,
                                                  row_ptr, edge_list, out);
}